// Round 6
// baseline (410.682 us; speedup 1.0000x reference)
//
#include <hip/hip_runtime.h>

// ---------------------------------------------------------------------------
// MultiHeadAttention: B=8, T=1024, E=256(head dim), H=8, TEMP=16
// 5 launches: prep(xcast+maskpack) | wtrans_all | gemm_qkv(merged N=6144) |
//             flash attn (8-wave, single-buf K/V, 2 blk/CU, defer-max) |
//             gemm_fc (64x64 tiles, 512 blocks)
// All matmuls: v_mfma_f32_16x16x32_bf16, fp32 accumulate.
// 1/TEMP folded as 0.25 into both Wq and Wk at transpose time.
// ---------------------------------------------------------------------------

typedef __attribute__((ext_vector_type(8))) short bf16x8;
typedef __attribute__((ext_vector_type(4))) float f32x4;
typedef __attribute__((ext_vector_type(4))) unsigned short u16x4;
typedef __attribute__((ext_vector_type(2))) unsigned int u32x2;
typedef __attribute__((ext_vector_type(4))) int i32x4;

#define B_DIM 8
#define T_DIM 1024
#define E_DIM 256
#define H_DIM 8

__device__ __forceinline__ unsigned short f2bf(float f) {
  unsigned u = __builtin_bit_cast(unsigned, f);
  u += 0x7FFFu + ((u >> 16) & 1u);   // RNE, finite values only
  return (unsigned short)(u >> 16);
}

__device__ __forceinline__ void gload_lds16(const void* g, void* l) {
  __builtin_amdgcn_global_load_lds(
      (const __attribute__((address_space(1))) void*)g,
      (__attribute__((address_space(3))) void*)l, 16, 0, 0);
}

__device__ __forceinline__ f32x4 mfma16(bf16x8 a, bf16x8 b, f32x4 c) {
  return __builtin_amdgcn_mfma_f32_16x16x32_bf16(a, b, c, 0, 0, 0);
}

// ------------------- prep: x->bf16 cast + mask bit-pack --------------------
// blocks 0..2047: xcast (one f32x4/thread). blocks 2048..3071: mask pack
// (32 int32 -> u32 of bits per thread).
__global__ __launch_bounds__(256) void prep_kernel(
    const float* __restrict__ x, unsigned short* __restrict__ xbf,
    const int* __restrict__ mask, unsigned* __restrict__ mpk) {
  int bid = blockIdx.x;
  if (bid < 2048) {
    int i = bid * 256 + threadIdx.x;
    f32x4 v = ((const f32x4*)x)[i];
    u16x4 o = { f2bf(v[0]), f2bf(v[1]), f2bf(v[2]), f2bf(v[3]) };
    ((u16x4*)xbf)[i] = o;
  } else {
    int i = (bid - 2048) * 256 + threadIdx.x;   // 262144 u32 total
    const i32x4* src = (const i32x4*)(mask + (size_t)i * 32);
    unsigned v = 0;
#pragma unroll
    for (int j = 0; j < 8; ++j) {
      i32x4 a = src[j];
      v |= (a[0] != 0 ? 1u : 0u) << (j * 4 + 0);
      v |= (a[1] != 0 ? 1u : 0u) << (j * 4 + 1);
      v |= (a[2] != 0 ? 1u : 0u) << (j * 4 + 2);
      v |= (a[3] != 0 ? 1u : 0u) << (j * 4 + 3);
    }
    mpk[i] = v;
  }
}

// ------------- all weight transposes + bf16 (+scale) in one launch ---------
// grid (128, 4): y=0,1,2 -> Wq,Wk,Wv [256][2048] (scale .25,.25,1) into wall;
// y=3 -> Wfc [2048][256] into wfcT.
__global__ __launch_bounds__(256) void wtrans_all(
    const float* __restrict__ Wq, const float* __restrict__ Wk,
    const float* __restrict__ Wv, const float* __restrict__ Wfc,
    unsigned short* __restrict__ wall, unsigned short* __restrict__ wfcT) {
  __shared__ unsigned short tile[64][65];
  const int which = blockIdx.y, bx = blockIdx.x, tid = threadIdx.x;
  const float* in;
  unsigned short* out;
  int K, N, n0, k0;
  float scale;
  if (which < 3) {
    in = which == 0 ? Wq : (which == 1 ? Wk : Wv);
    out = wall + (size_t)which * 2048 * 256;
    K = 256; N = 2048; scale = which == 2 ? 1.0f : 0.25f;
    n0 = (bx & 31) * 64; k0 = (bx >> 5) * 64;
  } else {
    in = Wfc; out = wfcT; K = 2048; N = 256; scale = 1.0f;
    n0 = (bx & 3) * 64; k0 = (bx >> 2) * 64;
  }
#pragma unroll
  for (int p = 0; p < 16; ++p) {
    int i = p * 256 + tid;
    int r = i >> 6, c = i & 63;
    tile[c][r] = f2bf(in[(size_t)(k0 + r) * N + n0 + c] * scale);
  }
  __syncthreads();
#pragma unroll
  for (int p = 0; p < 16; ++p) {
    int i = p * 256 + tid;
    int r = i >> 6, c = i & 63;
    out[(size_t)(n0 + r) * K + k0 + c] = tile[r][c];
  }
}

// --------------------- merged QKV GEMM (128x128, K=256) --------------------
// A=[8192][256] bf16, BT=[6144][256] bf16 (wqT|wkT|wvT).
// cols 0..4095 -> qk buffer [b][16][t][e] (heads 0-7 = Q, 8-15 = K);
// cols 4096..6143 -> v buffer [b][h][e][t] (transposed store).
__global__ __launch_bounds__(256) void gemm_qkv(
    const unsigned short* __restrict__ A, const unsigned short* __restrict__ BT,
    unsigned short* __restrict__ qk, unsigned short* __restrict__ vout) {
  __shared__ unsigned short As[128 * 64];
  __shared__ unsigned short Bs[128 * 64];
  const int tid = threadIdx.x;
  const int w = tid >> 6, l = tid & 63, lg = l >> 4, lr = l & 15;
  const int tn = blockIdx.x * 128, tm = blockIdx.y * 128;
  const int wm = (w >> 1) * 64, wn = (w & 1) * 64;

  f32x4 acc[4][4];
#pragma unroll
  for (int i = 0; i < 4; ++i)
#pragma unroll
    for (int j = 0; j < 4; ++j) acc[i][j] = (f32x4){0.f, 0.f, 0.f, 0.f};

  for (int kt = 0; kt < 256; kt += 64) {
#pragma unroll
    for (int j = 0; j < 4; ++j) {
      int d = j * 4096 + w * 1024 + l * 16;
      int row = d >> 7, cb = d & 127;
      gload_lds16((const char*)(A + (size_t)(tm + row) * 256 + kt) + (cb ^ ((row & 7) << 4)),
                  (char*)As + d);
    }
#pragma unroll
    for (int j = 0; j < 4; ++j) {
      int d = j * 4096 + w * 1024 + l * 16;
      int row = d >> 7, cb = d & 127;
      gload_lds16((const char*)(BT + (size_t)(tn + row) * 256 + kt) + (cb ^ ((row & 7) << 4)),
                  (char*)Bs + d);
    }
    __syncthreads();
#pragma unroll
    for (int c = 0; c < 2; ++c) {
      bf16x8 af[4], bfr[4];
#pragma unroll
      for (int mf = 0; mf < 4; ++mf) {
        int row = wm + mf * 16 + lr;
        af[mf] = *(const bf16x8*)((const char*)As + row * 128 +
                                  ((c * 64 + lg * 16) ^ ((row & 7) << 4)));
      }
#pragma unroll
      for (int nf = 0; nf < 4; ++nf) {
        int row = wn + nf * 16 + lr;
        bfr[nf] = *(const bf16x8*)((const char*)Bs + row * 128 +
                                   ((c * 64 + lg * 16) ^ ((row & 7) << 4)));
      }
#pragma unroll
      for (int mf = 0; mf < 4; ++mf)
#pragma unroll
        for (int nf = 0; nf < 4; ++nf)
          acc[mf][nf] = mfma16(af[mf], bfr[nf], acc[mf][nf]);
    }
    __syncthreads();
  }

  if (tn < 4096) {  // Q/K region: [b][16 heads][t][e]
#pragma unroll
    for (int mf = 0; mf < 4; ++mf)
#pragma unroll
      for (int nf = 0; nf < 4; ++nf) {
        int col = tn + wn + nf * 16 + lr;
        int row0 = tm + wm + mf * 16 + lg * 4;
        int h16 = col >> 8, e = col & 255;
#pragma unroll
        for (int r = 0; r < 4; ++r) {
          int rowm = row0 + r;
          int bi = rowm >> 10, t = rowm & 1023;
          qk[(((size_t)bi * 16 + h16) * T_DIM + t) * E_DIM + e] = f2bf(acc[mf][nf][r]);
        }
      }
  } else {  // V region: [b][h][e][t], 4 consecutive t per u16x4
#pragma unroll
    for (int mf = 0; mf < 4; ++mf)
#pragma unroll
      for (int nf = 0; nf < 4; ++nf) {
        int col = tn + wn + nf * 16 + lr;
        int row0 = tm + wm + mf * 16 + lg * 4;
        int bi = row0 >> 10, t0 = row0 & 1023;
        int hh = (col >> 8) - 16, e = col & 255;
        u16x4 pk = { f2bf(acc[mf][nf][0]), f2bf(acc[mf][nf][1]),
                     f2bf(acc[mf][nf][2]), f2bf(acc[mf][nf][3]) };
        *(u16x4*)&vout[(((size_t)bi * H_DIM + hh) * E_DIM + e) * T_DIM + t0] = pk;
      }
  }
}

// ------------------------------ flash attention ----------------------------
// 512 blocks x 512 thr (8 waves), 80 KB LDS -> 2 blocks/CU (cross-block
// overlap hides the single-buffer staging stall). Block = (bh, qt): 128 q
// rows; wave w owns rows w*16..w*16+15. Defer-max (THR=8) skips O-rescale
// when the running max doesn't grow. Swapped QK^T: S^T[kv][q].
// qk: [b][16][t][e] (heads 0-7 Q pre-scaled .25, 8-15 K pre-scaled .25).
// vtb: [b][h][e][t]. mpk: bit-packed mask (u64 = one 64-kv tile per q-row).
__global__ __launch_bounds__(512, 4) void attn_kernel(
    const unsigned short* __restrict__ qkb, const unsigned short* __restrict__ vtb,
    const unsigned long long* __restrict__ mpk,
    unsigned short* __restrict__ aout) {
  __shared__ unsigned short Kt[64 * 256];   // [kv][e], swizzled   (32KB)
  __shared__ unsigned short Vt[256 * 64];   // [e][kv], swizzled   (32KB)
  __shared__ unsigned short Pt[8][16 * 64]; // per-wave P [q][kv]  (16KB)

  const int tid = threadIdx.x;
  const int w = tid >> 6, l = tid & 63, lg = l >> 4, lr = l & 15;
  // XCD-aware swizzle: XCD x owns bh 8x..8x+7; q-tiles of one bh consecutive.
  const int bid = blockIdx.x;
  const int x = bid & 7, j = bid >> 3;
  const int bh = x * 8 + (j >> 3), qt = j & 7;
  const int b = bh >> 3, h = bh & 7;

  const unsigned short* qg =
      qkb + (((size_t)b * 16 + h) * T_DIM + qt * 128) * E_DIM;
  const unsigned short* kg = qkb + (((size_t)b * 16 + 8 + h) * T_DIM) * E_DIM;
  const char* vgc = (const char*)(vtb + (size_t)bh * E_DIM * T_DIM);
  const unsigned long long* mrow =
      mpk + ((size_t)b * T_DIM + qt * 128 + w * 16 + lr) * 16;

  // stage K/V tile kt (single buffer; all 8 waves cooperate)
  auto stageKV = [&](int kt) {
    const char* ksrc = (const char*)(kg + (size_t)(kt * 64) * E_DIM);
#pragma unroll
    for (int j2 = 0; j2 < 4; ++j2) {
      int d = j2 * 8192 + w * 1024 + l * 16;
      int row = d >> 9, cb = d & 511;
      gload_lds16(ksrc + row * 512 + (cb ^ ((row & 7) << 4)), (char*)Kt + d);
    }
#pragma unroll
    for (int j2 = 0; j2 < 4; ++j2) {
      int d = j2 * 8192 + w * 1024 + l * 16;
      int row = d >> 7, cb = d & 127;
      gload_lds16(vgc + (size_t)row * 2048 + kt * 128 + (cb ^ ((row & 7) << 4)),
                  (char*)Vt + d);
    }
  };

  stageKV(0);
  bf16x8 qf[8];
  {
    const unsigned short* qrow = qg + (size_t)(w * 16 + lr) * E_DIM + lg * 8;
#pragma unroll
    for (int c = 0; c < 8; ++c) qf[c] = *(const bf16x8*)(qrow + c * 32);
  }

  f32x4 O[16];
#pragma unroll
  for (int i = 0; i < 16; ++i) O[i] = (f32x4){0.f, 0.f, 0.f, 0.f};
  float m_run = -INFINITY, l_run = 0.f;

  for (int kt = 0; kt < 16; ++kt) {
    unsigned long long m64 = mrow[kt];
    __syncthreads();   // stage(kt) landed (barrier drains vmcnt)

    // ---- S^T = K * Q^T : D[kv][q], col(l&15)=q, row(lg*4+r)=kv
    f32x4 S[4];
#pragma unroll
    for (int i = 0; i < 4; ++i) S[i] = (f32x4){0.f, 0.f, 0.f, 0.f};
    __builtin_amdgcn_s_setprio(1);
#pragma unroll
    for (int kvf = 0; kvf < 4; ++kvf) {
      int row = kvf * 16 + lr;
      const char* abase = (const char*)Kt + row * 512;
      int swz = (row & 7) << 4;
#pragma unroll
      for (int c = 0; c < 8; ++c) {
        bf16x8 a = *(const bf16x8*)(abase + ((c * 64 + lg * 16) ^ swz));
        S[kvf] = mfma16(a, qf[c], S[kvf]);
      }
    }
    __builtin_amdgcn_s_setprio(0);

    // ---- mask + online softmax (lane owns q = w*16+lr; kv = kvf*16+lg*4+r)
    float p[4][4];
    float tmax = -INFINITY;
#pragma unroll
    for (int kvf = 0; kvf < 4; ++kvf) {
      unsigned nib = (unsigned)(m64 >> (kvf * 16 + lg * 4)) & 0xFu;
#pragma unroll
      for (int r = 0; r < 4; ++r) {
        float sv = S[kvf][r];
        if (nib & (1u << r)) sv = -INFINITY;
        p[kvf][r] = sv;
        tmax = fmaxf(tmax, sv);
      }
    }
    tmax = fmaxf(tmax, __shfl_xor(tmax, 16, 64));
    tmax = fmaxf(tmax, __shfl_xor(tmax, 32, 64));

    // defer-max (T13): only rescale when the max grew by > 8.
    // (NaN/-inf edge cases fall into the full path.)
    float m_old = m_run;
    int full = !__all(tmax - m_run <= 8.0f);
    if (full) m_run = fmaxf(m_run, tmax);
    float msafe = fmaxf(m_run, -1e30f);

    float rsum = 0.f;
#pragma unroll
    for (int kvf = 0; kvf < 4; ++kvf)
#pragma unroll
      for (int r = 0; r < 4; ++r) {
        float e = __expf(p[kvf][r] - msafe);  // -inf -> 0
        p[kvf][r] = e;
        rsum += e;
      }
    rsum += __shfl_xor(rsum, 16, 64);
    rsum += __shfl_xor(rsum, 32, 64);

    if (full) {
      float alpha = __expf(m_old - msafe);
      float av0 = __shfl(alpha, lg * 4 + 0, 64);
      float av1 = __shfl(alpha, lg * 4 + 1, 64);
      float av2 = __shfl(alpha, lg * 4 + 2, 64);
      float av3 = __shfl(alpha, lg * 4 + 3, 64);
#pragma unroll
      for (int nf = 0; nf < 16; ++nf) {
        O[nf][0] *= av0; O[nf][1] *= av1; O[nf][2] *= av2; O[nf][3] *= av3;
      }
      l_run = l_run * alpha + rsum;
    } else {
      l_run += rsum;
    }

    // ---- write P (bf16) to per-wave LDS, swizzled
    {
      char* pb = (char*)(Pt[w]) + lr * 128;
      int swz = (lr & 7) << 4;
#pragma unroll
      for (int kvf = 0; kvf < 4; ++kvf) {
        u32x2 pk;
        pk[0] = (unsigned)f2bf(p[kvf][0]) | ((unsigned)f2bf(p[kvf][1]) << 16);
        pk[1] = (unsigned)f2bf(p[kvf][2]) | ((unsigned)f2bf(p[kvf][3]) << 16);
        *(u32x2*)(pb + ((kvf * 32 + lg * 8) ^ swz)) = pk;
      }
    }

    // ---- PV: O[q][e] += P[q][kv] * V[kv][e]
    __builtin_amdgcn_s_setprio(1);
#pragma unroll
    for (int c2 = 0; c2 < 2; ++c2) {
      const char* pbase = (const char*)(Pt[w]) + lr * 128;
      bf16x8 pa = *(const bf16x8*)(pbase + ((c2 * 64 + lg * 16) ^ ((lr & 7) << 4)));
#pragma unroll
      for (int nf = 0; nf < 16; ++nf) {
        int vrow = nf * 16 + lr;
        bf16x8 vb = *(const bf16x8*)((const char*)Vt + vrow * 128 +
                                     ((c2 * 64 + lg * 16) ^ ((vrow & 7) << 4)));
        O[nf] = mfma16(pa, vb, O[nf]);
      }
    }
    __builtin_amdgcn_s_setprio(0);

    __syncthreads();   // all waves done reading Kt/Vt
    if (kt < 15) stageKV(kt + 1);   // safe to overwrite now
  }

  // ---- epilogue: O/l (0 if fully masked), store bf16 [b][t][h*256+e]
  float lv[4];
#pragma unroll
  for (int r = 0; r < 4; ++r) {
    float lval = __shfl(l_run, lg * 4 + r, 64);
    lv[r] = lval > 0.f ? 1.f / lval : 0.f;
  }
  const int qrow0 = qt * 128 + w * 16 + lg * 4;
  unsigned short* obase = aout + (size_t)(b * T_DIM) * 2048 + h * 256;
#pragma unroll
  for (int nf = 0; nf < 16; ++nf) {
#pragma unroll
    for (int r = 0; r < 4; ++r) {
      obase[(size_t)(qrow0 + r) * 2048 + nf * 16 + lr] = f2bf(O[nf][r] * lv[r]);
    }
  }
}

// --------------------- FC GEMM: 64x64 tiles, 512 blocks --------------------
// C[8192,256] = A[8192,2048] * BT[256,2048]^T + bias.  4 waves (2x2), each
// 32x32 (acc[2][2]); BK=64; f32 out.
__global__ __launch_bounds__(256) void gemm_fc(
    const unsigned short* __restrict__ A, const unsigned short* __restrict__ BT,
    const float* __restrict__ bias, float* __restrict__ C) {
  __shared__ unsigned short As[64 * 64];
  __shared__ unsigned short Bs[64 * 64];
  const int tid = threadIdx.x;
  const int w = tid >> 6, l = tid & 63, lg = l >> 4, lr = l & 15;
  const int tn = blockIdx.x * 64, tm = blockIdx.y * 64;
  const int wm = (w >> 1) * 32, wn = (w & 1) * 32;

  f32x4 acc[2][2];
#pragma unroll
  for (int i = 0; i < 2; ++i)
#pragma unroll
    for (int j = 0; j < 2; ++j) acc[i][j] = (f32x4){0.f, 0.f, 0.f, 0.f};

  for (int kt = 0; kt < 2048; kt += 64) {
#pragma unroll
    for (int j = 0; j < 2; ++j) {
      int d = j * 4096 + (tid & 255) * 16;
      int row = d >> 7, cb = d & 127;
      gload_lds16((const char*)(A + (size_t)(tm + row) * 2048 + kt) + (cb ^ ((row & 7) << 4)),
                  (char*)As + d);
    }
#pragma unroll
    for (int j = 0; j < 2; ++j) {
      int d = j * 4096 + (tid & 255) * 16;
      int row = d >> 7, cb = d & 127;
      gload_lds16((const char*)(BT + (size_t)(tn + row) * 2048 + kt) + (cb ^ ((row & 7) << 4)),
                  (char*)Bs + d);
    }
    __syncthreads();
#pragma unroll
    for (int c = 0; c < 2; ++c) {
      bf16x8 af[2], bfr[2];
#pragma unroll
      for (int mf = 0; mf < 2; ++mf) {
        int row = wm + mf * 16 + lr;
        af[mf] = *(const bf16x8*)((const char*)As + row * 128 +
                                  ((c * 64 + lg * 16) ^ ((row & 7) << 4)));
      }
#pragma unroll
      for (int nf = 0; nf < 2; ++nf) {
        int row = wn + nf * 16 + lr;
        bfr[nf] = *(const bf16x8*)((const char*)Bs + row * 128 +
                                   ((c * 64 + lg * 16) ^ ((row & 7) << 4)));
      }
#pragma unroll
      for (int mf = 0; mf < 2; ++mf)
#pragma unroll
        for (int nf = 0; nf < 2; ++nf)
          acc[mf][nf] = mfma16(af[mf], bfr[nf], acc[mf][nf]);
    }
    __syncthreads();
  }

#pragma unroll
  for (int mf = 0; mf < 2; ++mf)
#pragma unroll
    for (int nf = 0; nf < 2; ++nf) {
      int col = tn + wn + nf * 16 + lr;
      int row0 = tm + wm + mf * 16 + lg * 4;
      float bv = bias[col];
#pragma unroll
      for (int r = 0; r < 4; ++r)
        C[(size_t)(row0 + r) * 256 + col] = acc[mf][nf][r] + bv;
    }
}

// ------------------------------- launcher ----------------------------------
extern "C" void kernel_launch(void* const* d_in, const int* in_sizes, int n_in,
                              void* d_out, int out_size, void* d_ws, size_t ws_size,
                              hipStream_t stream) {
  (void)in_sizes; (void)n_in; (void)out_size; (void)ws_size;
  const float* x    = (const float*)d_in[0];
  const float* Wq   = (const float*)d_in[1];
  const float* Wk   = (const float*)d_in[2];
  const float* Wv   = (const float*)d_in[3];
  const float* Wfc  = (const float*)d_in[4];
  const float* bfc  = (const float*)d_in[5];
  const int* mask   = (const int*)d_in[6];
  float* out = (float*)d_out;

  char* ws = (char*)d_ws;
  unsigned short* xbf  = (unsigned short*)(ws + 0);          //   4 MB [8192][256]
  unsigned short* qkb  = (unsigned short*)(ws + 4194304);    //  64 MB [b][16][t][e]
  unsigned short* vbuf = (unsigned short*)(ws + 71303168);   //  32 MB [b][h][e][t]
  unsigned short* abuf = (unsigned short*)(ws + 104857600);  //  32 MB [8192][2048]
  unsigned short* wall = (unsigned short*)(ws + 138412032);  //   3 MB [6144][256]
  unsigned short* wfcT = (unsigned short*)(ws + 141557760);  //   1 MB [256][2048]
  unsigned*       mpk  = (unsigned*)(ws + 142606336);        //   1 MB packed mask

  prep_kernel<<<3072, 256, 0, stream>>>(x, xbf, mask, mpk);
  wtrans_all<<<dim3(128, 4), 256, 0, stream>>>(Wq, Wk, Wv, Wfc, wall, wfcT);
  gemm_qkv<<<dim3(48, 64), 256, 0, stream>>>(xbf, wall, qkb, vbuf);
  attn_kernel<<<512, 512, 0, stream>>>(qkb, vbuf,
                                       (const unsigned long long*)mpk, abuf);
  gemm_fc<<<dim3(4, 128), 256, 0, stream>>>(abuf, wfcT, bfc, out);
}

// Round 7
// 339.057 us; speedup vs baseline: 1.2112x; 1.2112x over previous
//
#include <hip/hip_runtime.h>

// ---------------------------------------------------------------------------
// MultiHeadAttention: B=8, T=1024, E=256(head dim), H=8, TEMP=16
// 5 launches: prep(xcast+maskpack) | wtrans_all | gemm_qkv(merged N=6144) |
//             flash attn (8-wave, KVBLK=32 dbuf, 2 blk/CU, defer-max) |
//             gemm_fc (64x64 tiles, 512 blocks)
// All matmuls: v_mfma_f32_16x16x32_bf16, fp32 accumulate.
// 1/TEMP folded as 0.25 into both Wq and Wk at transpose time.
// NOTE: __launch_bounds__ 2nd arg behaves as CUDA minBlocksPerCU on hipcc
// (observed r6: (512,4) -> 64-VGPR cap -> spill disaster). (512,2) -> cap 128.
// ---------------------------------------------------------------------------

typedef __attribute__((ext_vector_type(8))) short bf16x8;
typedef __attribute__((ext_vector_type(4))) float f32x4;
typedef __attribute__((ext_vector_type(4))) unsigned short u16x4;
typedef __attribute__((ext_vector_type(2))) unsigned int u32x2;
typedef __attribute__((ext_vector_type(4))) int i32x4;

#define B_DIM 8
#define T_DIM 1024
#define E_DIM 256
#define H_DIM 8

__device__ __forceinline__ unsigned short f2bf(float f) {
  unsigned u = __builtin_bit_cast(unsigned, f);
  u += 0x7FFFu + ((u >> 16) & 1u);   // RNE, finite values only
  return (unsigned short)(u >> 16);
}

__device__ __forceinline__ void gload_lds16(const void* g, void* l) {
  __builtin_amdgcn_global_load_lds(
      (const __attribute__((address_space(1))) void*)g,
      (__attribute__((address_space(3))) void*)l, 16, 0, 0);
}

__device__ __forceinline__ f32x4 mfma16(bf16x8 a, bf16x8 b, f32x4 c) {
  return __builtin_amdgcn_mfma_f32_16x16x32_bf16(a, b, c, 0, 0, 0);
}

// ------------------- prep: x->bf16 cast + mask bit-pack --------------------
__global__ __launch_bounds__(256) void prep_kernel(
    const float* __restrict__ x, unsigned short* __restrict__ xbf,
    const int* __restrict__ mask, unsigned* __restrict__ mpk) {
  int bid = blockIdx.x;
  if (bid < 2048) {
    int i = bid * 256 + threadIdx.x;
    f32x4 v = ((const f32x4*)x)[i];
    u16x4 o = { f2bf(v[0]), f2bf(v[1]), f2bf(v[2]), f2bf(v[3]) };
    ((u16x4*)xbf)[i] = o;
  } else {
    int i = (bid - 2048) * 256 + threadIdx.x;   // 262144 u32 total
    const i32x4* src = (const i32x4*)(mask + (size_t)i * 32);
    unsigned v = 0;
#pragma unroll
    for (int j = 0; j < 8; ++j) {
      i32x4 a = src[j];
      v |= (a[0] != 0 ? 1u : 0u) << (j * 4 + 0);
      v |= (a[1] != 0 ? 1u : 0u) << (j * 4 + 1);
      v |= (a[2] != 0 ? 1u : 0u) << (j * 4 + 2);
      v |= (a[3] != 0 ? 1u : 0u) << (j * 4 + 3);
    }
    mpk[i] = v;
  }
}

// ------------- all weight transposes + bf16 (+scale) in one launch ---------
__global__ __launch_bounds__(256) void wtrans_all(
    const float* __restrict__ Wq, const float* __restrict__ Wk,
    const float* __restrict__ Wv, const float* __restrict__ Wfc,
    unsigned short* __restrict__ wall, unsigned short* __restrict__ wfcT) {
  __shared__ unsigned short tile[64][65];
  const int which = blockIdx.y, bx = blockIdx.x, tid = threadIdx.x;
  const float* in;
  unsigned short* out;
  int K, N, n0, k0;
  float scale;
  if (which < 3) {
    in = which == 0 ? Wq : (which == 1 ? Wk : Wv);
    out = wall + (size_t)which * 2048 * 256;
    K = 256; N = 2048; scale = which == 2 ? 1.0f : 0.25f;
    n0 = (bx & 31) * 64; k0 = (bx >> 5) * 64;
  } else {
    in = Wfc; out = wfcT; K = 2048; N = 256; scale = 1.0f;
    n0 = (bx & 3) * 64; k0 = (bx >> 2) * 64;
  }
#pragma unroll
  for (int p = 0; p < 16; ++p) {
    int i = p * 256 + tid;
    int r = i >> 6, c = i & 63;
    tile[c][r] = f2bf(in[(size_t)(k0 + r) * N + n0 + c] * scale);
  }
  __syncthreads();
#pragma unroll
  for (int p = 0; p < 16; ++p) {
    int i = p * 256 + tid;
    int r = i >> 6, c = i & 63;
    out[(size_t)(n0 + r) * K + k0 + c] = tile[r][c];
  }
}

// --------------------- merged QKV GEMM (128x128, K=256) --------------------
__global__ __launch_bounds__(256) void gemm_qkv(
    const unsigned short* __restrict__ A, const unsigned short* __restrict__ BT,
    unsigned short* __restrict__ qk, unsigned short* __restrict__ vout) {
  __shared__ unsigned short As[128 * 64];
  __shared__ unsigned short Bs[128 * 64];
  const int tid = threadIdx.x;
  const int w = tid >> 6, l = tid & 63, lg = l >> 4, lr = l & 15;
  const int tn = blockIdx.x * 128, tm = blockIdx.y * 128;
  const int wm = (w >> 1) * 64, wn = (w & 1) * 64;

  f32x4 acc[4][4];
#pragma unroll
  for (int i = 0; i < 4; ++i)
#pragma unroll
    for (int j = 0; j < 4; ++j) acc[i][j] = (f32x4){0.f, 0.f, 0.f, 0.f};

  for (int kt = 0; kt < 256; kt += 64) {
#pragma unroll
    for (int j = 0; j < 4; ++j) {
      int d = j * 4096 + w * 1024 + l * 16;
      int row = d >> 7, cb = d & 127;
      gload_lds16((const char*)(A + (size_t)(tm + row) * 256 + kt) + (cb ^ ((row & 7) << 4)),
                  (char*)As + d);
    }
#pragma unroll
    for (int j = 0; j < 4; ++j) {
      int d = j * 4096 + w * 1024 + l * 16;
      int row = d >> 7, cb = d & 127;
      gload_lds16((const char*)(BT + (size_t)(tn + row) * 256 + kt) + (cb ^ ((row & 7) << 4)),
                  (char*)Bs + d);
    }
    __syncthreads();
#pragma unroll
    for (int c = 0; c < 2; ++c) {
      bf16x8 af[4], bfr[4];
#pragma unroll
      for (int mf = 0; mf < 4; ++mf) {
        int row = wm + mf * 16 + lr;
        af[mf] = *(const bf16x8*)((const char*)As + row * 128 +
                                  ((c * 64 + lg * 16) ^ ((row & 7) << 4)));
      }
#pragma unroll
      for (int nf = 0; nf < 4; ++nf) {
        int row = wn + nf * 16 + lr;
        bfr[nf] = *(const bf16x8*)((const char*)Bs + row * 128 +
                                   ((c * 64 + lg * 16) ^ ((row & 7) << 4)));
      }
#pragma unroll
      for (int mf = 0; mf < 4; ++mf)
#pragma unroll
        for (int nf = 0; nf < 4; ++nf)
          acc[mf][nf] = mfma16(af[mf], bfr[nf], acc[mf][nf]);
    }
    __syncthreads();
  }

  if (tn < 4096) {  // Q/K region: [b][16 heads][t][e]
#pragma unroll
    for (int mf = 0; mf < 4; ++mf)
#pragma unroll
      for (int nf = 0; nf < 4; ++nf) {
        int col = tn + wn + nf * 16 + lr;
        int row0 = tm + wm + mf * 16 + lg * 4;
        int h16 = col >> 8, e = col & 255;
#pragma unroll
        for (int r = 0; r < 4; ++r) {
          int rowm = row0 + r;
          int bi = rowm >> 10, t = rowm & 1023;
          qk[(((size_t)bi * 16 + h16) * T_DIM + t) * E_DIM + e] = f2bf(acc[mf][nf][r]);
        }
      }
  } else {  // V region: [b][h][e][t], 4 consecutive t per u16x4
#pragma unroll
    for (int mf = 0; mf < 4; ++mf)
#pragma unroll
      for (int nf = 0; nf < 4; ++nf) {
        int col = tn + wn + nf * 16 + lr;
        int row0 = tm + wm + mf * 16 + lg * 4;
        int bi = row0 >> 10, t0 = row0 & 1023;
        int hh = (col >> 8) - 16, e = col & 255;
        u16x4 pk = { f2bf(acc[mf][nf][0]), f2bf(acc[mf][nf][1]),
                     f2bf(acc[mf][nf][2]), f2bf(acc[mf][nf][3]) };
        *(u16x4*)&vout[(((size_t)bi * H_DIM + hh) * E_DIM + e) * T_DIM + t0] = pk;
      }
  }
}

// ------------------------------ flash attention ----------------------------
// 512 blocks x 512 thr (8 waves), KVBLK=32, double-buffered K/V.
// LDS = 2x16K (K) + 2x16K (Vt) + 8K (P) = 72KB -> 2 blocks/CU; VGPR cap 128
// via __launch_bounds__(512,2). Loop = round-4 structure: stage(kt+1) issued
// BEFORE compute(kt), single end-barrier per tile drains it after a full
// compute phase. Cross-block overlap (2/CU) hides softmax-vs-MFMA lockstep.
// qk: [b][16][t][e] (heads 0-7 Q, 8-15 K, both pre-scaled .25).
// vtb: [b][h][e][t]. mpk: bit-packed mask, u32 = one 32-kv tile per q-row.
// Swapped QK^T: S^T[kv][q], lane (l&15)=q owns one q-row's scores.
__global__ __launch_bounds__(512, 2) void attn_kernel(
    const unsigned short* __restrict__ qkb, const unsigned short* __restrict__ vtb,
    const unsigned* __restrict__ mpk,
    unsigned short* __restrict__ aout) {
  __shared__ unsigned short Kt[2][32 * 256];  // [kv][e], swz (row&7)<<4  (2x16KB)
  __shared__ unsigned short Vt[2][256 * 32];  // [e][kv], swz (row&3)<<4  (2x16KB)
  __shared__ unsigned short Pt[8][16 * 32];   // per-wave P [q][kv], swz  (8KB)

  const int tid = threadIdx.x;
  const int w = tid >> 6, l = tid & 63, lg = l >> 4, lr = l & 15;
  // XCD-aware swizzle: XCD x owns bh 8x..8x+7; q-tiles of one bh consecutive.
  const int bid = blockIdx.x;
  const int x = bid & 7, j = bid >> 3;
  const int bh = x * 8 + (j >> 3), qt = j & 7;
  const int b = bh >> 3, h = bh & 7;

  const unsigned short* qg =
      qkb + (((size_t)b * 16 + h) * T_DIM + qt * 128) * E_DIM;
  const unsigned short* kg = qkb + (((size_t)b * 16 + 8 + h) * T_DIM) * E_DIM;
  const char* vgc = (const char*)(vtb + (size_t)bh * E_DIM * T_DIM);
  // packed mask row for this lane's q row (32 u32 per row; one u32 per tile)
  const unsigned* mrow = mpk + ((size_t)b * T_DIM + qt * 128 + w * 16 + lr) * 32;

  // stage K/V tile kt (32 kv) into buffer bufi; 16KB each, 2 passes/thread
  auto stageKV = [&](int bufi, int kt) {
    const char* ksrc = (const char*)(kg + (size_t)(kt * 32) * E_DIM);
    char* kdst = (char*)Kt[bufi];
    char* vdst = (char*)Vt[bufi];
#pragma unroll
    for (int j2 = 0; j2 < 2; ++j2) {
      int d = j2 * 8192 + tid * 16;
      int row = d >> 9, cb = d & 511;
      gload_lds16(ksrc + row * 512 + (cb ^ ((row & 7) << 4)), kdst + d);
    }
#pragma unroll
    for (int j2 = 0; j2 < 2; ++j2) {
      int d = j2 * 8192 + tid * 16;
      int row = d >> 6, cb = d & 63;
      gload_lds16(vgc + (size_t)row * 2048 + kt * 64 + (cb ^ ((row & 3) << 4)),
                  vdst + d);
    }
  };

  stageKV(0, 0);
  bf16x8 qf[8];
  {
    const unsigned short* qrow = qg + (size_t)(w * 16 + lr) * E_DIM + lg * 8;
#pragma unroll
    for (int c = 0; c < 8; ++c) qf[c] = *(const bf16x8*)(qrow + c * 32);
  }

  f32x4 O[16];
#pragma unroll
  for (int i = 0; i < 16; ++i) O[i] = (f32x4){0.f, 0.f, 0.f, 0.f};
  float m_run = -INFINITY, l_run = 0.f;

  __syncthreads();   // stage(0) landed

  for (int kt = 0; kt < 32; ++kt) {
    const int cur = kt & 1;
    unsigned m32 = mrow[kt];
    if (kt < 31) stageKV(cur ^ 1, kt + 1);   // in flight across this compute

    // ---- S^T = K * Q^T : D[kv][q], col(l&15)=q, row(kvf*16+lg*4+r)=kv
    f32x4 S[2];
#pragma unroll
    for (int i = 0; i < 2; ++i) S[i] = (f32x4){0.f, 0.f, 0.f, 0.f};
    __builtin_amdgcn_s_setprio(1);
#pragma unroll
    for (int kvf = 0; kvf < 2; ++kvf) {
      int row = kvf * 16 + lr;
      const char* abase = (const char*)Kt[cur] + row * 512;
      int swz = (row & 7) << 4;
#pragma unroll
      for (int c = 0; c < 8; ++c) {
        bf16x8 a = *(const bf16x8*)(abase + ((c * 64 + lg * 16) ^ swz));
        S[kvf] = mfma16(a, qf[c], S[kvf]);
      }
    }
    __builtin_amdgcn_s_setprio(0);

    // ---- mask + online softmax (lane owns q=w*16+lr; kv=kvf*16+lg*4+r)
    float p[2][4];
    float tmax = -INFINITY;
#pragma unroll
    for (int kvf = 0; kvf < 2; ++kvf) {
      unsigned nib = (m32 >> (kvf * 16 + lg * 4)) & 0xFu;
#pragma unroll
      for (int r = 0; r < 4; ++r) {
        float sv = S[kvf][r];
        if (nib & (1u << r)) sv = -INFINITY;
        p[kvf][r] = sv;
        tmax = fmaxf(tmax, sv);
      }
    }
    tmax = fmaxf(tmax, __shfl_xor(tmax, 16, 64));
    tmax = fmaxf(tmax, __shfl_xor(tmax, 32, 64));

    // defer-max (T13): only rescale when the max grew by > 8.
    float m_old = m_run;
    int full = !__all(tmax - m_run <= 8.0f);
    if (full) m_run = fmaxf(m_run, tmax);
    float msafe = fmaxf(m_run, -1e30f);

    float rsum = 0.f;
#pragma unroll
    for (int kvf = 0; kvf < 2; ++kvf)
#pragma unroll
      for (int r = 0; r < 4; ++r) {
        float e = __expf(p[kvf][r] - msafe);  // -inf -> 0
        p[kvf][r] = e;
        rsum += e;
      }
    rsum += __shfl_xor(rsum, 16, 64);
    rsum += __shfl_xor(rsum, 32, 64);

    if (full) {
      float alpha = __expf(m_old - msafe);
      float av0 = __shfl(alpha, lg * 4 + 0, 64);
      float av1 = __shfl(alpha, lg * 4 + 1, 64);
      float av2 = __shfl(alpha, lg * 4 + 2, 64);
      float av3 = __shfl(alpha, lg * 4 + 3, 64);
#pragma unroll
      for (int nf = 0; nf < 16; ++nf) {
        O[nf][0] *= av0; O[nf][1] *= av1; O[nf][2] *= av2; O[nf][3] *= av3;
      }
      l_run = l_run * alpha + rsum;
    } else {
      l_run += rsum;
    }

    // ---- write P (bf16) to per-wave LDS row q=lr (64B), swz (lr&3)<<4
    {
      char* pb = (char*)(Pt[w]) + lr * 64;
      int swz = (lr & 3) << 4;
#pragma unroll
      for (int kvf = 0; kvf < 2; ++kvf) {
        u32x2 pk;
        pk[0] = (unsigned)f2bf(p[kvf][0]) | ((unsigned)f2bf(p[kvf][1]) << 16);
        pk[1] = (unsigned)f2bf(p[kvf][2]) | ((unsigned)f2bf(p[kvf][3]) << 16);
        *(u32x2*)(pb + ((kvf * 32 + lg * 8) ^ swz)) = pk;
      }
    }

    // ---- PV: O[q][e] += P[q][kv] * V[kv][e]  (one K=32 MFMA per e-tile)
    __builtin_amdgcn_s_setprio(1);
    {
      bf16x8 pa = *(const bf16x8*)((const char*)(Pt[w]) + lr * 64 +
                                   ((lg * 16) ^ ((lr & 3) << 4)));
#pragma unroll
      for (int nf = 0; nf < 16; ++nf) {
        int vrow = nf * 16 + lr;
        bf16x8 vb = *(const bf16x8*)((const char*)Vt[cur] + vrow * 64 +
                                     ((lg * 16) ^ ((vrow & 3) << 4)));
        O[nf] = mfma16(pa, vb, O[nf]);
      }
    }
    __builtin_amdgcn_s_setprio(0);

    // single barrier per tile: drains stage(kt+1) (issued a full compute
    // phase ago) and closes reads of buf[cur] before it's restaged.
    __syncthreads();
  }

  // ---- epilogue: O/l (0 if fully masked), store bf16 [b][t][h*256+e]
  float lv[4];
#pragma unroll
  for (int r = 0; r < 4; ++r) {
    float lval = __shfl(l_run, lg * 4 + r, 64);
    lv[r] = lval > 0.f ? 1.f / lval : 0.f;
  }
  const int qrow0 = qt * 128 + w * 16 + lg * 4;
  unsigned short* obase = aout + (size_t)(b * T_DIM) * 2048 + h * 256;
#pragma unroll
  for (int nf = 0; nf < 16; ++nf) {
#pragma unroll
    for (int r = 0; r < 4; ++r) {
      obase[(size_t)(qrow0 + r) * 2048 + nf * 16 + lr] = f2bf(O[nf][r] * lv[r]);
    }
  }
}

// --------------------- FC GEMM: 64x64 tiles, 512 blocks --------------------
__global__ __launch_bounds__(256) void gemm_fc(
    const unsigned short* __restrict__ A, const unsigned short* __restrict__ BT,
    const float* __restrict__ bias, float* __restrict__ C) {
  __shared__ unsigned short As[64 * 64];
  __shared__ unsigned short Bs[64 * 64];
  const int tid = threadIdx.x;
  const int w = tid >> 6, l = tid & 63, lg = l >> 4, lr = l & 15;
  const int tn = blockIdx.x * 64, tm = blockIdx.y * 64;
  const int wm = (w >> 1) * 32, wn = (w & 1) * 32;

  f32x4 acc[2][2];
#pragma unroll
  for (int i = 0; i < 2; ++i)
#pragma unroll
    for (int j = 0; j < 2; ++j) acc[i][j] = (f32x4){0.f, 0.f, 0.f, 0.f};

  for (int kt = 0; kt < 2048; kt += 64) {
#pragma unroll
    for (int j = 0; j < 2; ++j) {
      int d = j * 4096 + (tid & 255) * 16;
      int row = d >> 7, cb = d & 127;
      gload_lds16((const char*)(A + (size_t)(tm + row) * 2048 + kt) + (cb ^ ((row & 7) << 4)),
                  (char*)As + d);
    }
#pragma unroll
    for (int j = 0; j < 2; ++j) {
      int d = j * 4096 + (tid & 255) * 16;
      int row = d >> 7, cb = d & 127;
      gload_lds16((const char*)(BT + (size_t)(tn + row) * 2048 + kt) + (cb ^ ((row & 7) << 4)),
                  (char*)Bs + d);
    }
    __syncthreads();
#pragma unroll
    for (int c = 0; c < 2; ++c) {
      bf16x8 af[2], bfr[2];
#pragma unroll
      for (int mf = 0; mf < 2; ++mf) {
        int row = wm + mf * 16 + lr;
        af[mf] = *(const bf16x8*)((const char*)As + row * 128 +
                                  ((c * 64 + lg * 16) ^ ((row & 7) << 4)));
      }
#pragma unroll
      for (int nf = 0; nf < 2; ++nf) {
        int row = wn + nf * 16 + lr;
        bfr[nf] = *(const bf16x8*)((const char*)Bs + row * 128 +
                                   ((c * 64 + lg * 16) ^ ((row & 7) << 4)));
      }
#pragma unroll
      for (int mf = 0; mf < 2; ++mf)
#pragma unroll
        for (int nf = 0; nf < 2; ++nf)
          acc[mf][nf] = mfma16(af[mf], bfr[nf], acc[mf][nf]);
    }
    __syncthreads();
  }

#pragma unroll
  for (int mf = 0; mf < 2; ++mf)
#pragma unroll
    for (int nf = 0; nf < 2; ++nf) {
      int col = tn + wn + nf * 16 + lr;
      int row0 = tm + wm + mf * 16 + lg * 4;
      float bv = bias[col];
#pragma unroll
      for (int r = 0; r < 4; ++r)
        C[(size_t)(row0 + r) * 256 + col] = acc[mf][nf][r] + bv;
    }
}

// ------------------------------- launcher ----------------------------------
extern "C" void kernel_launch(void* const* d_in, const int* in_sizes, int n_in,
                              void* d_out, int out_size, void* d_ws, size_t ws_size,
                              hipStream_t stream) {
  (void)in_sizes; (void)n_in; (void)out_size; (void)ws_size;
  const float* x    = (const float*)d_in[0];
  const float* Wq   = (const float*)d_in[1];
  const float* Wk   = (const float*)d_in[2];
  const float* Wv   = (const float*)d_in[3];
  const float* Wfc  = (const float*)d_in[4];
  const float* bfc  = (const float*)d_in[5];
  const int* mask   = (const int*)d_in[6];
  float* out = (float*)d_out;

  char* ws = (char*)d_ws;
  unsigned short* xbf  = (unsigned short*)(ws + 0);          //   4 MB [8192][256]
  unsigned short* qkb  = (unsigned short*)(ws + 4194304);    //  64 MB [b][16][t][e]
  unsigned short* vbuf = (unsigned short*)(ws + 71303168);   //  32 MB [b][h][e][t]
  unsigned short* abuf = (unsigned short*)(ws + 104857600);  //  32 MB [8192][2048]
  unsigned short* wall = (unsigned short*)(ws + 138412032);  //   3 MB [6144][256]
  unsigned short* wfcT = (unsigned short*)(ws + 141557760);  //   1 MB [256][2048]
  unsigned*       mpk  = (unsigned*)(ws + 142606336);        //   1 MB packed mask

  prep_kernel<<<3072, 256, 0, stream>>>(x, xbf, mask, mpk);
  wtrans_all<<<dim3(128, 4), 256, 0, stream>>>(Wq, Wk, Wv, Wfc, wall, wfcT);
  gemm_qkv<<<dim3(48, 64), 256, 0, stream>>>(xbf, wall, qkb, vbuf);
  attn_kernel<<<512, 512, 0, stream>>>(qkb, vbuf, mpk, abuf);
  gemm_fc<<<dim3(4, 128), 256, 0, stream>>>(abuf, wfcT, bfc, out);
}

// Round 8
// 304.500 us; speedup vs baseline: 1.3487x; 1.1135x over previous
//
#include <hip/hip_runtime.h>

// ---------------------------------------------------------------------------
// MultiHeadAttention: B=8, T=1024, E=256(head dim), H=8, TEMP=16
// 4 launches: prep_all(xcast+maskpack+wtrans) | gemm_qkv(merged N=6144) |
//             flash attn (8-wave, KVBLK=64, single-buf 80KB, 2 blk/CU) |
//             gemm_fc (64x64 tiles, 512 blocks)
// All matmuls: v_mfma_f32_16x16x32_bf16, fp32 accumulate.
// 1/TEMP folded as 0.25 into both Wq and Wk at transpose time.
// launch_bounds note (r6/r7 evidence): (512,4) caps VGPR at 64 -> spills;
// (512,2) caps at >=128 (r7: natural 80, no spill). Residency target here:
// 80KB LDS * 2 = 160KB exact (the r6 config that measured 43% occupancy).
// ---------------------------------------------------------------------------

typedef __attribute__((ext_vector_type(8))) short bf16x8;
typedef __attribute__((ext_vector_type(4))) float f32x4;
typedef __attribute__((ext_vector_type(4))) unsigned short u16x4;
typedef __attribute__((ext_vector_type(2))) unsigned int u32x2;
typedef __attribute__((ext_vector_type(4))) int i32x4;

#define B_DIM 8
#define T_DIM 1024
#define E_DIM 256
#define H_DIM 8

__device__ __forceinline__ unsigned short f2bf(float f) {
  unsigned u = __builtin_bit_cast(unsigned, f);
  u += 0x7FFFu + ((u >> 16) & 1u);   // RNE, finite values only
  return (unsigned short)(u >> 16);
}

__device__ __forceinline__ void gload_lds16(const void* g, void* l) {
  __builtin_amdgcn_global_load_lds(
      (const __attribute__((address_space(1))) void*)g,
      (__attribute__((address_space(3))) void*)l, 16, 0, 0);
}

__device__ __forceinline__ f32x4 mfma16(bf16x8 a, bf16x8 b, f32x4 c) {
  return __builtin_amdgcn_mfma_f32_16x16x32_bf16(a, b, c, 0, 0, 0);
}

// ---------- prep_all: xcast | mask bit-pack | weight transposes ------------
// bid 0..2047: x->bf16 (one f32x4/thread). 2048..3071: mask pack (32 int32 ->
// u32/thread). 3072..3583: weight transpose (which=(bid-3072)>>7, 128 blk ea).
__global__ __launch_bounds__(256) void prep_all(
    const float* __restrict__ x, unsigned short* __restrict__ xbf,
    const int* __restrict__ mask, unsigned* __restrict__ mpk,
    const float* __restrict__ Wq, const float* __restrict__ Wk,
    const float* __restrict__ Wv, const float* __restrict__ Wfc,
    unsigned short* __restrict__ wall, unsigned short* __restrict__ wfcT) {
  __shared__ unsigned short tile[64][65];
  const int bid = blockIdx.x, tid = threadIdx.x;
  if (bid < 2048) {
    int i = bid * 256 + tid;
    f32x4 v = ((const f32x4*)x)[i];
    u16x4 o = { f2bf(v[0]), f2bf(v[1]), f2bf(v[2]), f2bf(v[3]) };
    ((u16x4*)xbf)[i] = o;
    return;
  }
  if (bid < 3072) {
    int i = (bid - 2048) * 256 + tid;   // 262144 u32 total
    const i32x4* src = (const i32x4*)(mask + (size_t)i * 32);
    unsigned v = 0;
#pragma unroll
    for (int j = 0; j < 8; ++j) {
      i32x4 a = src[j];
      v |= (a[0] != 0 ? 1u : 0u) << (j * 4 + 0);
      v |= (a[1] != 0 ? 1u : 0u) << (j * 4 + 1);
      v |= (a[2] != 0 ? 1u : 0u) << (j * 4 + 2);
      v |= (a[3] != 0 ? 1u : 0u) << (j * 4 + 3);
    }
    mpk[i] = v;
    return;
  }
  const int which = (bid - 3072) >> 7, bx = (bid - 3072) & 127;
  const float* in;
  unsigned short* out;
  int K, N, n0, k0;
  float scale;
  if (which < 3) {
    in = which == 0 ? Wq : (which == 1 ? Wk : Wv);
    out = wall + (size_t)which * 2048 * 256;
    K = 256; N = 2048; scale = which == 2 ? 1.0f : 0.25f;
    n0 = (bx & 31) * 64; k0 = (bx >> 5) * 64;
  } else {
    in = Wfc; out = wfcT; K = 2048; N = 256; scale = 1.0f;
    n0 = (bx & 3) * 64; k0 = (bx >> 2) * 64;
  }
#pragma unroll
  for (int p = 0; p < 16; ++p) {
    int i = p * 256 + tid;
    int r = i >> 6, c = i & 63;
    tile[c][r] = f2bf(in[(size_t)(k0 + r) * N + n0 + c] * scale);
  }
  __syncthreads();
#pragma unroll
  for (int p = 0; p < 16; ++p) {
    int i = p * 256 + tid;
    int r = i >> 6, c = i & 63;
    out[(size_t)(n0 + r) * K + k0 + c] = tile[r][c];
  }
}

// --------------------- merged QKV GEMM (128x128, K=256) --------------------
__global__ __launch_bounds__(256) void gemm_qkv(
    const unsigned short* __restrict__ A, const unsigned short* __restrict__ BT,
    unsigned short* __restrict__ qk, unsigned short* __restrict__ vout) {
  __shared__ unsigned short As[128 * 64];
  __shared__ unsigned short Bs[128 * 64];
  const int tid = threadIdx.x;
  const int w = tid >> 6, l = tid & 63, lg = l >> 4, lr = l & 15;
  const int tn = blockIdx.x * 128, tm = blockIdx.y * 128;
  const int wm = (w >> 1) * 64, wn = (w & 1) * 64;

  f32x4 acc[4][4];
#pragma unroll
  for (int i = 0; i < 4; ++i)
#pragma unroll
    for (int j = 0; j < 4; ++j) acc[i][j] = (f32x4){0.f, 0.f, 0.f, 0.f};

  for (int kt = 0; kt < 256; kt += 64) {
#pragma unroll
    for (int j = 0; j < 4; ++j) {
      int d = j * 4096 + w * 1024 + l * 16;
      int row = d >> 7, cb = d & 127;
      gload_lds16((const char*)(A + (size_t)(tm + row) * 256 + kt) + (cb ^ ((row & 7) << 4)),
                  (char*)As + d);
    }
#pragma unroll
    for (int j = 0; j < 4; ++j) {
      int d = j * 4096 + w * 1024 + l * 16;
      int row = d >> 7, cb = d & 127;
      gload_lds16((const char*)(BT + (size_t)(tn + row) * 256 + kt) + (cb ^ ((row & 7) << 4)),
                  (char*)Bs + d);
    }
    __syncthreads();
#pragma unroll
    for (int c = 0; c < 2; ++c) {
      bf16x8 af[4], bfr[4];
#pragma unroll
      for (int mf = 0; mf < 4; ++mf) {
        int row = wm + mf * 16 + lr;
        af[mf] = *(const bf16x8*)((const char*)As + row * 128 +
                                  ((c * 64 + lg * 16) ^ ((row & 7) << 4)));
      }
#pragma unroll
      for (int nf = 0; nf < 4; ++nf) {
        int row = wn + nf * 16 + lr;
        bfr[nf] = *(const bf16x8*)((const char*)Bs + row * 128 +
                                   ((c * 64 + lg * 16) ^ ((row & 7) << 4)));
      }
#pragma unroll
      for (int mf = 0; mf < 4; ++mf)
#pragma unroll
        for (int nf = 0; nf < 4; ++nf)
          acc[mf][nf] = mfma16(af[mf], bfr[nf], acc[mf][nf]);
    }
    __syncthreads();
  }

  if (tn < 4096) {  // Q/K region: [b][16 heads][t][e]
#pragma unroll
    for (int mf = 0; mf < 4; ++mf)
#pragma unroll
      for (int nf = 0; nf < 4; ++nf) {
        int col = tn + wn + nf * 16 + lr;
        int row0 = tm + wm + mf * 16 + lg * 4;
        int h16 = col >> 8, e = col & 255;
#pragma unroll
        for (int r = 0; r < 4; ++r) {
          int rowm = row0 + r;
          int bi = rowm >> 10, t = rowm & 1023;
          qk[(((size_t)bi * 16 + h16) * T_DIM + t) * E_DIM + e] = f2bf(acc[mf][nf][r]);
        }
      }
  } else {  // V region: [b][h][e][t], 4 consecutive t per u16x4
#pragma unroll
    for (int mf = 0; mf < 4; ++mf)
#pragma unroll
      for (int nf = 0; nf < 4; ++nf) {
        int col = tn + wn + nf * 16 + lr;
        int row0 = tm + wm + mf * 16 + lg * 4;
        int bi = row0 >> 10, t0 = row0 & 1023;
        int hh = (col >> 8) - 16, e = col & 255;
        u16x4 pk = { f2bf(acc[mf][nf][0]), f2bf(acc[mf][nf][1]),
                     f2bf(acc[mf][nf][2]), f2bf(acc[mf][nf][3]) };
        *(u16x4*)&vout[(((size_t)bi * H_DIM + hh) * E_DIM + e) * T_DIM + t0] = pk;
      }
  }
}

// ------------------------------ flash attention ----------------------------
// 512 blocks x 512 thr (8 waves). KVBLK=64, single-buffer K/V.
// LDS = Kt 32K + Vt 32K + Pt 16K = 80KB -> 2 blocks/CU (160KB exact; the r6
// config that measured 43% occupancy). Cross-block overlap hides the
// stage-drain stall at the top barrier (m114). Defer-max (THR=8). Swapped
// QK^T: S^T[kv][q], lane (l&15)=q owns one q-row's scores.
// qk: [b][16][t][e] (heads 0-7 Q, 8-15 K, both pre-scaled .25).
// vtb: [b][h][e][t]. mpk: bit-packed mask (u64 = one 64-kv tile per q-row).
__global__ __launch_bounds__(512, 2) void attn_kernel(
    const unsigned short* __restrict__ qkb, const unsigned short* __restrict__ vtb,
    const unsigned long long* __restrict__ mpk,
    unsigned short* __restrict__ aout) {
  __shared__ unsigned short Kt[64 * 256];   // [kv][e], swz (row&7)<<4 (32KB)
  __shared__ unsigned short Vt[256 * 64];   // [e][kv], swz (row&7)<<4 (32KB)
  __shared__ unsigned short Pt[8][16 * 64]; // per-wave P, swz (lr&7)<<4 (16KB)

  const int tid = threadIdx.x;
  const int w = tid >> 6, l = tid & 63, lg = l >> 4, lr = l & 15;
  // XCD-aware swizzle: XCD x owns bh 8x..8x+7; q-tiles of one bh consecutive.
  const int bid = blockIdx.x;
  const int x = bid & 7, j = bid >> 3;
  const int bh = x * 8 + (j >> 3), qt = j & 7;
  const int b = bh >> 3, h = bh & 7;

  const unsigned short* qg =
      qkb + (((size_t)b * 16 + h) * T_DIM + qt * 128) * E_DIM;
  const unsigned short* kg = qkb + (((size_t)b * 16 + 8 + h) * T_DIM) * E_DIM;
  const char* vgc = (const char*)(vtb + (size_t)bh * E_DIM * T_DIM);
  const unsigned long long* mrow =
      mpk + ((size_t)b * T_DIM + qt * 128 + w * 16 + lr) * 16;

  // stage K/V tile kt (64 kv) into the single buffer; all 8 waves cooperate
  auto stageKV = [&](int kt) {
    const char* ksrc = (const char*)(kg + (size_t)(kt * 64) * E_DIM);
#pragma unroll
    for (int j2 = 0; j2 < 4; ++j2) {
      int d = j2 * 8192 + w * 1024 + l * 16;
      int row = d >> 9, cb = d & 511;
      gload_lds16(ksrc + row * 512 + (cb ^ ((row & 7) << 4)), (char*)Kt + d);
    }
#pragma unroll
    for (int j2 = 0; j2 < 4; ++j2) {
      int d = j2 * 8192 + w * 1024 + l * 16;
      int row = d >> 7, cb = d & 127;
      gload_lds16(vgc + (size_t)row * 2048 + kt * 128 + (cb ^ ((row & 7) << 4)),
                  (char*)Vt + d);
    }
  };

  stageKV(0);
  bf16x8 qf[8];
  {
    const unsigned short* qrow = qg + (size_t)(w * 16 + lr) * E_DIM + lg * 8;
#pragma unroll
    for (int c = 0; c < 8; ++c) qf[c] = *(const bf16x8*)(qrow + c * 32);
  }

  f32x4 O[16];
#pragma unroll
  for (int i = 0; i < 16; ++i) O[i] = (f32x4){0.f, 0.f, 0.f, 0.f};
  float m_run = -INFINITY, l_run = 0.f;
  unsigned long long m_cur = mrow[0];

  for (int kt = 0; kt < 16; ++kt) {
    __syncthreads();   // stage(kt) landed (barrier drains vmcnt)
    unsigned long long m_next = (kt < 15) ? mrow[kt + 1] : 0ull;  // overlaps QK

    // ---- S^T = K * Q^T : D[kv][q], col(l&15)=q, row(kvf*16+lg*4+r)=kv
    f32x4 S[4];
#pragma unroll
    for (int i = 0; i < 4; ++i) S[i] = (f32x4){0.f, 0.f, 0.f, 0.f};
    __builtin_amdgcn_s_setprio(1);
#pragma unroll
    for (int kvf = 0; kvf < 4; ++kvf) {
      int row = kvf * 16 + lr;
      const char* abase = (const char*)Kt + row * 512;
      int swz = (row & 7) << 4;
#pragma unroll
      for (int c = 0; c < 8; ++c) {
        bf16x8 a = *(const bf16x8*)(abase + ((c * 64 + lg * 16) ^ swz));
        S[kvf] = mfma16(a, qf[c], S[kvf]);
      }
    }
    __builtin_amdgcn_s_setprio(0);

    // ---- mask + online softmax (lane owns q=w*16+lr; kv=kvf*16+lg*4+r)
    float p[4][4];
    float tmax = -INFINITY;
#pragma unroll
    for (int kvf = 0; kvf < 4; ++kvf) {
      unsigned nib = (unsigned)(m_cur >> (kvf * 16 + lg * 4)) & 0xFu;
#pragma unroll
      for (int r = 0; r < 4; ++r) {
        float sv = S[kvf][r];
        if (nib & (1u << r)) sv = -INFINITY;
        p[kvf][r] = sv;
        tmax = fmaxf(tmax, sv);
      }
    }
    tmax = fmaxf(tmax, __shfl_xor(tmax, 16, 64));
    tmax = fmaxf(tmax, __shfl_xor(tmax, 32, 64));

    // defer-max (T13): only rescale when the max grew by > 8.
    float m_old = m_run;
    int full = !__all(tmax - m_run <= 8.0f);
    if (full) m_run = fmaxf(m_run, tmax);
    float msafe = fmaxf(m_run, -1e30f);

    float rsum = 0.f;
#pragma unroll
    for (int kvf = 0; kvf < 4; ++kvf)
#pragma unroll
      for (int r = 0; r < 4; ++r) {
        float e = __expf(p[kvf][r] - msafe);  // -inf -> 0
        p[kvf][r] = e;
        rsum += e;
      }
    rsum += __shfl_xor(rsum, 16, 64);
    rsum += __shfl_xor(rsum, 32, 64);

    if (full) {
      float alpha = __expf(m_old - msafe);
      float av0 = __shfl(alpha, lg * 4 + 0, 64);
      float av1 = __shfl(alpha, lg * 4 + 1, 64);
      float av2 = __shfl(alpha, lg * 4 + 2, 64);
      float av3 = __shfl(alpha, lg * 4 + 3, 64);
#pragma unroll
      for (int nf = 0; nf < 16; ++nf) {
        O[nf][0] *= av0; O[nf][1] *= av1; O[nf][2] *= av2; O[nf][3] *= av3;
      }
      l_run = l_run * alpha + rsum;
    } else {
      l_run += rsum;
    }

    // ---- write P (bf16) to per-wave LDS, swizzled
    {
      char* pb = (char*)(Pt[w]) + lr * 128;
      int swz = (lr & 7) << 4;
#pragma unroll
      for (int kvf = 0; kvf < 4; ++kvf) {
        u32x2 pk;
        pk[0] = (unsigned)f2bf(p[kvf][0]) | ((unsigned)f2bf(p[kvf][1]) << 16);
        pk[1] = (unsigned)f2bf(p[kvf][2]) | ((unsigned)f2bf(p[kvf][3]) << 16);
        *(u32x2*)(pb + ((kvf * 32 + lg * 8) ^ swz)) = pk;
      }
    }

    // ---- PV: O[q][e] += P[q][kv] * V[kv][e]
    __builtin_amdgcn_s_setprio(1);
#pragma unroll
    for (int c2 = 0; c2 < 2; ++c2) {
      const char* pbase = (const char*)(Pt[w]) + lr * 128;
      bf16x8 pa = *(const bf16x8*)(pbase + ((c2 * 64 + lg * 16) ^ ((lr & 7) << 4)));
#pragma unroll
      for (int nf = 0; nf < 16; ++nf) {
        int vrow = nf * 16 + lr;
        bf16x8 vb = *(const bf16x8*)((const char*)Vt + vrow * 128 +
                                     ((c2 * 64 + lg * 16) ^ ((vrow & 7) << 4)));
        O[nf] = mfma16(pa, vb, O[nf]);
      }
    }
    __builtin_amdgcn_s_setprio(0);

    __syncthreads();   // all waves done reading Kt/Vt
    if (kt < 15) { stageKV(kt + 1); m_cur = m_next; }
  }

  // ---- epilogue: O/l (0 if fully masked), store bf16 [b][t][h*256+e]
  float lv[4];
#pragma unroll
  for (int r = 0; r < 4; ++r) {
    float lval = __shfl(l_run, lg * 4 + r, 64);
    lv[r] = lval > 0.f ? 1.f / lval : 0.f;
  }
  const int qrow0 = qt * 128 + w * 16 + lg * 4;
  unsigned short* obase = aout + (size_t)(b * T_DIM) * 2048 + h * 256;
#pragma unroll
  for (int nf = 0; nf < 16; ++nf) {
#pragma unroll
    for (int r = 0; r < 4; ++r) {
      obase[(size_t)(qrow0 + r) * 2048 + nf * 16 + lr] = f2bf(O[nf][r] * lv[r]);
    }
  }
}

// --------------------- FC GEMM: 64x64 tiles, 512 blocks --------------------
__global__ __launch_bounds__(256) void gemm_fc(
    const unsigned short* __restrict__ A, const unsigned short* __restrict__ BT,
    const float* __restrict__ bias, float* __restrict__ C) {
  __shared__ unsigned short As[64 * 64];
  __shared__ unsigned short Bs[64 * 64];
  const int tid = threadIdx.x;
  const int w = tid >> 6, l = tid & 63, lg = l >> 4, lr = l & 15;
  const int tn = blockIdx.x * 64, tm = blockIdx.y * 64;
  const int wm = (w >> 1) * 32, wn = (w & 1) * 32;

  f32x4 acc[2][2];
#pragma unroll
  for (int i = 0; i < 2; ++i)
#pragma unroll
    for (int j = 0; j < 2; ++j) acc[i][j] = (f32x4){0.f, 0.f, 0.f, 0.f};

  for (int kt = 0; kt < 2048; kt += 64) {
#pragma unroll
    for (int j = 0; j < 2; ++j) {
      int d = j * 4096 + (tid & 255) * 16;
      int row = d >> 7, cb = d & 127;
      gload_lds16((const char*)(A + (size_t)(tm + row) * 2048 + kt) + (cb ^ ((row & 7) << 4)),
                  (char*)As + d);
    }
#pragma unroll
    for (int j = 0; j < 2; ++j) {
      int d = j * 4096 + (tid & 255) * 16;
      int row = d >> 7, cb = d & 127;
      gload_lds16((const char*)(BT + (size_t)(tn + row) * 2048 + kt) + (cb ^ ((row & 7) << 4)),
                  (char*)Bs + d);
    }
    __syncthreads();
#pragma unroll
    for (int c = 0; c < 2; ++c) {
      bf16x8 af[2], bfr[2];
#pragma unroll
      for (int mf = 0; mf < 2; ++mf) {
        int row = wm + mf * 16 + lr;
        af[mf] = *(const bf16x8*)((const char*)As + row * 128 +
                                  ((c * 64 + lg * 16) ^ ((row & 7) << 4)));
      }
#pragma unroll
      for (int nf = 0; nf < 2; ++nf) {
        int row = wn + nf * 16 + lr;
        bfr[nf] = *(const bf16x8*)((const char*)Bs + row * 128 +
                                   ((c * 64 + lg * 16) ^ ((row & 7) << 4)));
      }
#pragma unroll
      for (int mf = 0; mf < 2; ++mf)
#pragma unroll
        for (int nf = 0; nf < 2; ++nf)
          acc[mf][nf] = mfma16(af[mf], bfr[nf], acc[mf][nf]);
    }
    __syncthreads();
  }

#pragma unroll
  for (int mf = 0; mf < 2; ++mf)
#pragma unroll
    for (int nf = 0; nf < 2; ++nf) {
      int col = tn + wn + nf * 16 + lr;
      int row0 = tm + wm + mf * 16 + lg * 4;
      float bv = bias[col];
#pragma unroll
      for (int r = 0; r < 4; ++r)
        C[(size_t)(row0 + r) * 256 + col] = acc[mf][nf][r] + bv;
    }
}

// ------------------------------- launcher ----------------------------------
extern "C" void kernel_launch(void* const* d_in, const int* in_sizes, int n_in,
                              void* d_out, int out_size, void* d_ws, size_t ws_size,
                              hipStream_t stream) {
  (void)in_sizes; (void)n_in; (void)out_size; (void)ws_size;
  const float* x    = (const float*)d_in[0];
  const float* Wq   = (const float*)d_in[1];
  const float* Wk   = (const float*)d_in[2];
  const float* Wv   = (const float*)d_in[3];
  const float* Wfc  = (const float*)d_in[4];
  const float* bfc  = (const float*)d_in[5];
  const int* mask   = (const int*)d_in[6];
  float* out = (float*)d_out;

  char* ws = (char*)d_ws;
  unsigned short* xbf  = (unsigned short*)(ws + 0);          //   4 MB [8192][256]
  unsigned short* qkb  = (unsigned short*)(ws + 4194304);    //  64 MB [b][16][t][e]
  unsigned short* vbuf = (unsigned short*)(ws + 71303168);   //  32 MB [b][h][e][t]
  unsigned short* abuf = (unsigned short*)(ws + 104857600);  //  32 MB [8192][2048]
  unsigned short* wall = (unsigned short*)(ws + 138412032);  //   3 MB [6144][256]
  unsigned short* wfcT = (unsigned short*)(ws + 141557760);  //   1 MB [256][2048]
  unsigned*       mpk  = (unsigned*)(ws + 142606336);        //   1 MB packed mask

  prep_all<<<3584, 256, 0, stream>>>(x, xbf, mask, mpk, Wq, Wk, Wv, Wfc,
                                     wall, wfcT);
  gemm_qkv<<<dim3(48, 64), 256, 0, stream>>>(xbf, wall, qkb, vbuf);
  attn_kernel<<<512, 512, 0, stream>>>(qkb, vbuf,
                                       (const unsigned long long*)mpk, abuf);
  gemm_fc<<<dim3(4, 128), 256, 0, stream>>>(abuf, wfcT, bfc, out);
}

// Round 10
// 290.640 us; speedup vs baseline: 1.4130x; 1.0477x over previous
//
#include <hip/hip_runtime.h>

// ---------------------------------------------------------------------------
// MultiHeadAttention: B=8, T=1024, E=256(head dim), H=8, TEMP=16
// 4 launches: prep_all(xcast+maskpack+wtrans) | gemm_qkv(256x128, 512thr) |
//             flash attn (8-wave, KVBLK=64, single-buf 80KB) |
//             gemm_fc (64x64 tiles, BK=128, 512 blocks)
// All matmuls: v_mfma_f32_16x16x32_bf16, fp32 accumulate.
// 1/TEMP folded as 0.25 into both Wq and Wk at transpose time.
// Register reality (r8): attn total regs = 104 VGPR + ~64 AGPR -> 1 blk/CU.
// ---------------------------------------------------------------------------

typedef __attribute__((ext_vector_type(8))) short bf16x8;
typedef __attribute__((ext_vector_type(4))) float f32x4;
typedef __attribute__((ext_vector_type(4))) unsigned short u16x4;
typedef __attribute__((ext_vector_type(2))) unsigned int u32x2;
typedef __attribute__((ext_vector_type(4))) int i32x4;

#define B_DIM 8
#define T_DIM 1024
#define E_DIM 256
#define H_DIM 8

__device__ __forceinline__ unsigned short f2bf(float f) {
  unsigned u = __builtin_bit_cast(unsigned, f);
  u += 0x7FFFu + ((u >> 16) & 1u);   // RNE, finite values only
  return (unsigned short)(u >> 16);
}

__device__ __forceinline__ void gload_lds16(const void* g, void* l) {
  __builtin_amdgcn_global_load_lds(
      (const __attribute__((address_space(1))) void*)g,
      (__attribute__((address_space(3))) void*)l, 16, 0, 0);
}

__device__ __forceinline__ f32x4 mfma16(bf16x8 a, bf16x8 b, f32x4 c) {
  return __builtin_amdgcn_mfma_f32_16x16x32_bf16(a, b, c, 0, 0, 0);
}

// ---------- prep_all: xcast | mask bit-pack | weight transposes ------------
__global__ __launch_bounds__(256) void prep_all(
    const float* __restrict__ x, unsigned short* __restrict__ xbf,
    const int* __restrict__ mask, unsigned* __restrict__ mpk,
    const float* __restrict__ Wq, const float* __restrict__ Wk,
    const float* __restrict__ Wv, const float* __restrict__ Wfc,
    unsigned short* __restrict__ wall, unsigned short* __restrict__ wfcT) {
  __shared__ unsigned short tile[64][65];
  const int bid = blockIdx.x, tid = threadIdx.x;
  if (bid < 2048) {
    int i = bid * 256 + tid;
    f32x4 v = ((const f32x4*)x)[i];
    u16x4 o = { f2bf(v[0]), f2bf(v[1]), f2bf(v[2]), f2bf(v[3]) };
    ((u16x4*)xbf)[i] = o;
    return;
  }
  if (bid < 3072) {
    int i = (bid - 2048) * 256 + tid;   // 262144 u32 total
    const i32x4* src = (const i32x4*)(mask + (size_t)i * 32);
    unsigned v = 0;
#pragma unroll
    for (int j = 0; j < 8; ++j) {
      i32x4 a = src[j];
      v |= (a[0] != 0 ? 1u : 0u) << (j * 4 + 0);
      v |= (a[1] != 0 ? 1u : 0u) << (j * 4 + 1);
      v |= (a[2] != 0 ? 1u : 0u) << (j * 4 + 2);
      v |= (a[3] != 0 ? 1u : 0u) << (j * 4 + 3);
    }
    mpk[i] = v;
    return;
  }
  const int which = (bid - 3072) >> 7, bx = (bid - 3072) & 127;
  const float* in;
  unsigned short* out;
  int K, N, n0, k0;
  float scale;
  if (which < 3) {
    in = which == 0 ? Wq : (which == 1 ? Wk : Wv);
    out = wall + (size_t)which * 2048 * 256;
    K = 256; N = 2048; scale = which == 2 ? 1.0f : 0.25f;
    n0 = (bx & 31) * 64; k0 = (bx >> 5) * 64;
  } else {
    in = Wfc; out = wfcT; K = 2048; N = 256; scale = 1.0f;
    n0 = (bx & 3) * 64; k0 = (bx >> 2) * 64;
  }
#pragma unroll
  for (int p = 0; p < 16; ++p) {
    int i = p * 256 + tid;
    int r = i >> 6, c = i & 63;
    tile[c][r] = f2bf(in[(size_t)(k0 + r) * N + n0 + c] * scale);
  }
  __syncthreads();
#pragma unroll
  for (int p = 0; p < 16; ++p) {
    int i = p * 256 + tid;
    int r = i >> 6, c = i & 63;
    out[(size_t)(n0 + r) * K + k0 + c] = tile[r][c];
  }
}

// ---------------- merged QKV GEMM: 256x128 tiles, 512 thr ------------------
// A=[8192][256] bf16, BT=[6144][256] bf16 (wqT|wkT|wvT). Grid (48,32).
// 8 waves (4m x 2n), each 64x64 (acc 4x4). LDS 48KB -> 2-3 blocks/CU.
// cols 0..4095 -> qk [b][16][t][e] (heads 0-7 Q, 8-15 K); 4096+ -> V
// [b][h][e][t] transposed store.
__global__ __launch_bounds__(512) void gemm_qkv(
    const unsigned short* __restrict__ A, const unsigned short* __restrict__ BT,
    unsigned short* __restrict__ qk, unsigned short* __restrict__ vout) {
  __shared__ unsigned short As[256 * 64];
  __shared__ unsigned short Bs[128 * 64];
  const int tid = threadIdx.x;
  const int w = tid >> 6, l = tid & 63, lg = l >> 4, lr = l & 15;
  const int tn = blockIdx.x * 128, tm = blockIdx.y * 256;
  const int wm = (w >> 1) * 64, wn = (w & 1) * 64;

  f32x4 acc[4][4];
#pragma unroll
  for (int i = 0; i < 4; ++i)
#pragma unroll
    for (int j = 0; j < 4; ++j) acc[i][j] = (f32x4){0.f, 0.f, 0.f, 0.f};

  for (int kt = 0; kt < 256; kt += 64) {
#pragma unroll
    for (int j = 0; j < 4; ++j) {
      int d = j * 8192 + tid * 16;
      int row = d >> 7, cb = d & 127;
      gload_lds16((const char*)(A + (size_t)(tm + row) * 256 + kt) + (cb ^ ((row & 7) << 4)),
                  (char*)As + d);
    }
#pragma unroll
    for (int j = 0; j < 2; ++j) {
      int d = j * 8192 + tid * 16;
      int row = d >> 7, cb = d & 127;
      gload_lds16((const char*)(BT + (size_t)(tn + row) * 256 + kt) + (cb ^ ((row & 7) << 4)),
                  (char*)Bs + d);
    }
    __syncthreads();
#pragma unroll
    for (int c = 0; c < 2; ++c) {
      bf16x8 af[4], bfr[4];
#pragma unroll
      for (int mf = 0; mf < 4; ++mf) {
        int row = wm + mf * 16 + lr;
        af[mf] = *(const bf16x8*)((const char*)As + row * 128 +
                                  ((c * 64 + lg * 16) ^ ((row & 7) << 4)));
      }
#pragma unroll
      for (int nf = 0; nf < 4; ++nf) {
        int row = wn + nf * 16 + lr;
        bfr[nf] = *(const bf16x8*)((const char*)Bs + row * 128 +
                                   ((c * 64 + lg * 16) ^ ((row & 7) << 4)));
      }
#pragma unroll
      for (int mf = 0; mf < 4; ++mf)
#pragma unroll
        for (int nf = 0; nf < 4; ++nf)
          acc[mf][nf] = mfma16(af[mf], bfr[nf], acc[mf][nf]);
    }
    __syncthreads();
  }

  if (tn < 4096) {  // Q/K region: [b][16 heads][t][e]
#pragma unroll
    for (int mf = 0; mf < 4; ++mf)
#pragma unroll
      for (int nf = 0; nf < 4; ++nf) {
        int col = tn + wn + nf * 16 + lr;
        int row0 = tm + wm + mf * 16 + lg * 4;
        int h16 = col >> 8, e = col & 255;
#pragma unroll
        for (int r = 0; r < 4; ++r) {
          int rowm = row0 + r;
          int bi = rowm >> 10, t = rowm & 1023;
          qk[(((size_t)bi * 16 + h16) * T_DIM + t) * E_DIM + e] = f2bf(acc[mf][nf][r]);
        }
      }
  } else {  // V region: [b][h][e][t], 4 consecutive t per u16x4
#pragma unroll
    for (int mf = 0; mf < 4; ++mf)
#pragma unroll
      for (int nf = 0; nf < 4; ++nf) {
        int col = tn + wn + nf * 16 + lr;
        int row0 = tm + wm + mf * 16 + lg * 4;
        int bi = row0 >> 10, t0 = row0 & 1023;
        int hh = (col >> 8) - 16, e = col & 255;
        u16x4 pk = { f2bf(acc[mf][nf][0]), f2bf(acc[mf][nf][1]),
                     f2bf(acc[mf][nf][2]), f2bf(acc[mf][nf][3]) };
        *(u16x4*)&vout[(((size_t)bi * H_DIM + hh) * E_DIM + e) * T_DIM + t0] = pk;
      }
  }
}

// ------------------------------ flash attention ----------------------------
// (unchanged from r8 -- best measured config: 128.6us, VGPR 104, no spill)
__global__ __launch_bounds__(512, 2) void attn_kernel(
    const unsigned short* __restrict__ qkb, const unsigned short* __restrict__ vtb,
    const unsigned long long* __restrict__ mpk,
    unsigned short* __restrict__ aout) {
  __shared__ unsigned short Kt[64 * 256];   // [kv][e], swz (row&7)<<4 (32KB)
  __shared__ unsigned short Vt[256 * 64];   // [e][kv], swz (row&7)<<4 (32KB)
  __shared__ unsigned short Pt[8][16 * 64]; // per-wave P, swz (lr&7)<<4 (16KB)

  const int tid = threadIdx.x;
  const int w = tid >> 6, l = tid & 63, lg = l >> 4, lr = l & 15;
  const int bid = blockIdx.x;
  const int x = bid & 7, j = bid >> 3;
  const int bh = x * 8 + (j >> 3), qt = j & 7;
  const int b = bh >> 3, h = bh & 7;

  const unsigned short* qg =
      qkb + (((size_t)b * 16 + h) * T_DIM + qt * 128) * E_DIM;
  const unsigned short* kg = qkb + (((size_t)b * 16 + 8 + h) * T_DIM) * E_DIM;
  const char* vgc = (const char*)(vtb + (size_t)bh * E_DIM * T_DIM);
  const unsigned long long* mrow =
      mpk + ((size_t)b * T_DIM + qt * 128 + w * 16 + lr) * 16;

  auto stageKV = [&](int kt) {
    const char* ksrc = (const char*)(kg + (size_t)(kt * 64) * E_DIM);
#pragma unroll
    for (int j2 = 0; j2 < 4; ++j2) {
      int d = j2 * 8192 + w * 1024 + l * 16;
      int row = d >> 9, cb = d & 511;
      gload_lds16(ksrc + row * 512 + (cb ^ ((row & 7) << 4)), (char*)Kt + d);
    }
#pragma unroll
    for (int j2 = 0; j2 < 4; ++j2) {
      int d = j2 * 8192 + w * 1024 + l * 16;
      int row = d >> 7, cb = d & 127;
      gload_lds16(vgc + (size_t)row * 2048 + kt * 128 + (cb ^ ((row & 7) << 4)),
                  (char*)Vt + d);
    }
  };

  stageKV(0);
  bf16x8 qf[8];
  {
    const unsigned short* qrow = qg + (size_t)(w * 16 + lr) * E_DIM + lg * 8;
#pragma unroll
    for (int c = 0; c < 8; ++c) qf[c] = *(const bf16x8*)(qrow + c * 32);
  }

  f32x4 O[16];
#pragma unroll
  for (int i = 0; i < 16; ++i) O[i] = (f32x4){0.f, 0.f, 0.f, 0.f};
  float m_run = -INFINITY, l_run = 0.f;
  unsigned long long m_cur = mrow[0];

  for (int kt = 0; kt < 16; ++kt) {
    __syncthreads();   // stage(kt) landed (barrier drains vmcnt)
    unsigned long long m_next = (kt < 15) ? mrow[kt + 1] : 0ull;  // overlaps QK

    f32x4 S[4];
#pragma unroll
    for (int i = 0; i < 4; ++i) S[i] = (f32x4){0.f, 0.f, 0.f, 0.f};
    __builtin_amdgcn_s_setprio(1);
#pragma unroll
    for (int kvf = 0; kvf < 4; ++kvf) {
      int row = kvf * 16 + lr;
      const char* abase = (const char*)Kt + row * 512;
      int swz = (row & 7) << 4;
#pragma unroll
      for (int c = 0; c < 8; ++c) {
        bf16x8 a = *(const bf16x8*)(abase + ((c * 64 + lg * 16) ^ swz));
        S[kvf] = mfma16(a, qf[c], S[kvf]);
      }
    }
    __builtin_amdgcn_s_setprio(0);

    float p[4][4];
    float tmax = -INFINITY;
#pragma unroll
    for (int kvf = 0; kvf < 4; ++kvf) {
      unsigned nib = (unsigned)(m_cur >> (kvf * 16 + lg * 4)) & 0xFu;
#pragma unroll
      for (int r = 0; r < 4; ++r) {
        float sv = S[kvf][r];
        if (nib & (1u << r)) sv = -INFINITY;
        p[kvf][r] = sv;
        tmax = fmaxf(tmax, sv);
      }
    }
    tmax = fmaxf(tmax, __shfl_xor(tmax, 16, 64));
    tmax = fmaxf(tmax, __shfl_xor(tmax, 32, 64));

    float m_old = m_run;
    int full = !__all(tmax - m_run <= 8.0f);
    if (full) m_run = fmaxf(m_run, tmax);
    float msafe = fmaxf(m_run, -1e30f);

    float rsum = 0.f;
#pragma unroll
    for (int kvf = 0; kvf < 4; ++kvf)
#pragma unroll
      for (int r = 0; r < 4; ++r) {
        float e = __expf(p[kvf][r] - msafe);  // -inf -> 0
        p[kvf][r] = e;
        rsum += e;
      }
    rsum += __shfl_xor(rsum, 16, 64);
    rsum += __shfl_xor(rsum, 32, 64);

    if (full) {
      float alpha = __expf(m_old - msafe);
      float av0 = __shfl(alpha, lg * 4 + 0, 64);
      float av1 = __shfl(alpha, lg * 4 + 1, 64);
      float av2 = __shfl(alpha, lg * 4 + 2, 64);
      float av3 = __shfl(alpha, lg * 4 + 3, 64);
#pragma unroll
      for (int nf = 0; nf < 16; ++nf) {
        O[nf][0] *= av0; O[nf][1] *= av1; O[nf][2] *= av2; O[nf][3] *= av3;
      }
      l_run = l_run * alpha + rsum;
    } else {
      l_run += rsum;
    }

    {
      char* pb = (char*)(Pt[w]) + lr * 128;
      int swz = (lr & 7) << 4;
#pragma unroll
      for (int kvf = 0; kvf < 4; ++kvf) {
        u32x2 pk;
        pk[0] = (unsigned)f2bf(p[kvf][0]) | ((unsigned)f2bf(p[kvf][1]) << 16);
        pk[1] = (unsigned)f2bf(p[kvf][2]) | ((unsigned)f2bf(p[kvf][3]) << 16);
        *(u32x2*)(pb + ((kvf * 32 + lg * 8) ^ swz)) = pk;
      }
    }

    __builtin_amdgcn_s_setprio(1);
#pragma unroll
    for (int c2 = 0; c2 < 2; ++c2) {
      const char* pbase = (const char*)(Pt[w]) + lr * 128;
      bf16x8 pa = *(const bf16x8*)(pbase + ((c2 * 64 + lg * 16) ^ ((lr & 7) << 4)));
#pragma unroll
      for (int nf = 0; nf < 16; ++nf) {
        int vrow = nf * 16 + lr;
        bf16x8 vb = *(const bf16x8*)((const char*)Vt + vrow * 128 +
                                     ((c2 * 64 + lg * 16) ^ ((vrow & 7) << 4)));
        O[nf] = mfma16(pa, vb, O[nf]);
      }
    }
    __builtin_amdgcn_s_setprio(0);

    __syncthreads();   // all waves done reading Kt/Vt
    if (kt < 15) { stageKV(kt + 1); m_cur = m_next; }
  }

  float lv[4];
#pragma unroll
  for (int r = 0; r < 4; ++r) {
    float lval = __shfl(l_run, lg * 4 + r, 64);
    lv[r] = lval > 0.f ? 1.f / lval : 0.f;
  }
  const int qrow0 = qt * 128 + w * 16 + lg * 4;
  unsigned short* obase = aout + (size_t)(b * T_DIM) * 2048 + h * 256;
#pragma unroll
  for (int nf = 0; nf < 16; ++nf) {
#pragma unroll
    for (int r = 0; r < 4; ++r) {
      obase[(size_t)(qrow0 + r) * 2048 + nf * 16 + lr] = f2bf(O[nf][r] * lv[r]);
    }
  }
}

// --------------- FC GEMM: 64x64 tiles, BK=128, 512 blocks ------------------
// C[8192,256] = A[8192,2048] * BT[256,2048]^T + bias. 16 k-iters (barriers
// halved vs BK=64). LDS 32KB -> 4 blocks/CU by LDS.
__global__ __launch_bounds__(256) void gemm_fc(
    const unsigned short* __restrict__ A, const unsigned short* __restrict__ BT,
    const float* __restrict__ bias, float* __restrict__ C) {
  __shared__ unsigned short As[64 * 128];
  __shared__ unsigned short Bs[64 * 128];
  const int tid = threadIdx.x;
  const int w = tid >> 6, l = tid & 63, lg = l >> 4, lr = l & 15;
  const int tn = blockIdx.x * 64, tm = blockIdx.y * 64;
  const int wm = (w >> 1) * 32, wn = (w & 1) * 32;

  f32x4 acc[2][2];
#pragma unroll
  for (int i = 0; i < 2; ++i)
#pragma unroll
    for (int j = 0; j < 2; ++j) acc[i][j] = (f32x4){0.f, 0.f, 0.f, 0.f};

  for (int kt = 0; kt < 2048; kt += 128) {
#pragma unroll
    for (int j = 0; j < 4; ++j) {
      int d = j * 4096 + tid * 16;
      int row = d >> 8, cb = d & 255;
      gload_lds16((const char*)(A + (size_t)(tm + row) * 2048 + kt) + (cb ^ ((row & 7) << 4)),
                  (char*)As + d);
    }
#pragma unroll
    for (int j = 0; j < 4; ++j) {
      int d = j * 4096 + tid * 16;
      int row = d >> 8, cb = d & 255;
      gload_lds16((const char*)(BT + (size_t)(tn + row) * 2048 + kt) + (cb ^ ((row & 7) << 4)),
                  (char*)Bs + d);
    }
    __syncthreads();
#pragma unroll
    for (int c = 0; c < 4; ++c) {
      bf16x8 af[2], bfr[2];
#pragma unroll
      for (int mf = 0; mf < 2; ++mf) {
        int row = wm + mf * 16 + lr;
        af[mf] = *(const bf16x8*)((const char*)As + row * 256 +
                                  ((c * 64 + lg * 16) ^ ((row & 7) << 4)));
      }
#pragma unroll
      for (int nf = 0; nf < 2; ++nf) {
        int row = wn + nf * 16 + lr;
        bfr[nf] = *(const bf16x8*)((const char*)Bs + row * 256 +
                                   ((c * 64 + lg * 16) ^ ((row & 7) << 4)));
      }
#pragma unroll
      for (int mf = 0; mf < 2; ++mf)
#pragma unroll
        for (int nf = 0; nf < 2; ++nf)
          acc[mf][nf] = mfma16(af[mf], bfr[nf], acc[mf][nf]);
    }
    __syncthreads();
  }

#pragma unroll
  for (int mf = 0; mf < 2; ++mf)
#pragma unroll
    for (int nf = 0; nf < 2; ++nf) {
      int col = tn + wn + nf * 16 + lr;
      int row0 = tm + wm + mf * 16 + lg * 4;
      float bv = bias[col];
#pragma unroll
      for (int r = 0; r < 4; ++r)
        C[(size_t)(row0 + r) * 256 + col] = acc[mf][nf][r] + bv;
    }
}

// ------------------------------- launcher ----------------------------------
extern "C" void kernel_launch(void* const* d_in, const int* in_sizes, int n_in,
                              void* d_out, int out_size, void* d_ws, size_t ws_size,
                              hipStream_t stream) {
  (void)in_sizes; (void)n_in; (void)out_size; (void)ws_size;
  const float* x    = (const float*)d_in[0];
  const float* Wq   = (const float*)d_in[1];
  const float* Wk   = (const float*)d_in[2];
  const float* Wv   = (const float*)d_in[3];
  const float* Wfc  = (const float*)d_in[4];
  const float* bfc  = (const float*)d_in[5];
  const int* mask   = (const int*)d_in[6];
  float* out = (float*)d_out;

  char* ws = (char*)d_ws;
  unsigned short* xbf  = (unsigned short*)(ws + 0);          //   4 MB [8192][256]
  unsigned short* qkb  = (unsigned short*)(ws + 4194304);    //  64 MB [b][16][t][e]
  unsigned short* vbuf = (unsigned short*)(ws + 71303168);   //  32 MB [b][h][e][t]
  unsigned short* abuf = (unsigned short*)(ws + 104857600);  //  32 MB [8192][2048]
  unsigned short* wall = (unsigned short*)(ws + 138412032);  //   3 MB [6144][256]
  unsigned short* wfcT = (unsigned short*)(ws + 141557760);  //   1 MB [256][2048]
  unsigned*       mpk  = (unsigned*)(ws + 142606336);        //   1 MB packed mask

  prep_all<<<3584, 256, 0, stream>>>(x, xbf, mask, mpk, Wq, Wk, Wv, Wfc,
                                     wall, wfcT);
  gemm_qkv<<<dim3(48, 32), 512, 0, stream>>>(xbf, wall, qkb, vbuf);
  attn_kernel<<<512, 512, 0, stream>>>(qkb, vbuf,
                                       (const unsigned long long*)mpk, abuf);
  gemm_fc<<<dim3(4, 128), 256, 0, stream>>>(abuf, wfcT, bfc, out);
}